// Round 8
// baseline (166.625 us; speedup 1.0000x reference)
//
#include <hip/hip_runtime.h>
#include <stdint.h>

#define T_TOK  2048
#define HID    1024
#define INTERN 2048
#define NEXP   8
#define MAXPOS 5248   // max 128-aligned routed rows

typedef __attribute__((ext_vector_type(8))) short          bf16x8;
typedef __attribute__((ext_vector_type(4))) float          f32x4;
typedef __attribute__((ext_vector_type(8))) unsigned short u16x8;
typedef __attribute__((ext_vector_type(4))) unsigned short u16x4;

__device__ __forceinline__ unsigned short f32_to_bf16(float f) {
  unsigned int u = __float_as_uint(f);
  unsigned int r = (u + 0x7FFFu + ((u >> 16) & 1u)) >> 16;
  return (unsigned short)r;
}

__device__ __forceinline__ float bf16_to_f32(unsigned short h) {
  unsigned int u = ((unsigned int)h) << 16;
  return __uint_as_float(u);
}

__device__ __forceinline__ void gload_lds16(const void* g, void* l) {
  __builtin_amdgcn_global_load_lds(
      (const __attribute__((address_space(1))) unsigned int*)g,
      (__attribute__((address_space(3))) unsigned int*)l, 16, 0, 0);
}

__device__ __forceinline__ u16x8 cvt8(float4 a, float4 b) {
  u16x8 w;
  w[0] = f32_to_bf16(a.x); w[1] = f32_to_bf16(a.y);
  w[2] = f32_to_bf16(a.z); w[3] = f32_to_bf16(a.w);
  w[4] = f32_to_bf16(b.x); w[5] = f32_to_bf16(b.y);
  w[6] = f32_to_bf16(b.z); w[7] = f32_to_bf16(b.w);
  return w;
}

#define WAIT_VM0()    asm volatile("s_waitcnt vmcnt(0)" ::: "memory")
#define WAIT_VM4()    asm volatile("s_waitcnt vmcnt(4)" ::: "memory")
#define WAIT_LGKM0()  asm volatile("s_waitcnt lgkmcnt(0)" ::: "memory")
#define SCHED_FENCE() __builtin_amdgcn_sched_barrier(0)

// ---------------- routing ----------------
__global__ void route_kernel(const int* __restrict__ tki,
                             const float* __restrict__ tkw,
                             int* __restrict__ counts,
                             int* __restrict__ offsets,
                             int* __restrict__ tok_list,
                             float* __restrict__ w_list,
                             int* __restrict__ pos_map,
                             float* __restrict__ wgt_map) {
  __shared__ int scnt[NEXP];
  __shared__ int soff[NEXP];
  int tid = threadIdx.x;
  if (tid < NEXP) scnt[tid] = 0;
  __syncthreads();
  for (int t = tid; t < T_TOK; t += 256) {
    int e0 = tki[2 * t] & 7;
    int e1 = tki[2 * t + 1] & 7;
    float w0 = tkw[2 * t];
    float w1 = tkw[2 * t + 1];
    if (e0 == e1) {
      int p = atomicAdd(&scnt[e0], 1);
      tok_list[e0 * T_TOK + p] = t;
      w_list [e0 * T_TOK + p] = w0 + w1;
      pos_map[2 * t]     = (p << 3) | e0;
      wgt_map[2 * t]     = w0 + w1;
      pos_map[2 * t + 1] = -1;
      wgt_map[2 * t + 1] = 0.0f;
    } else {
      int p = atomicAdd(&scnt[e0], 1);
      tok_list[e0 * T_TOK + p] = t;
      w_list [e0 * T_TOK + p] = w0;
      pos_map[2 * t]     = (p << 3) | e0;
      wgt_map[2 * t]     = w0;
      int q = atomicAdd(&scnt[e1], 1);
      tok_list[e1 * T_TOK + q] = t;
      w_list [e1 * T_TOK + q] = w1;
      pos_map[2 * t + 1] = (q << 3) | e1;
      wgt_map[2 * t + 1] = w1;
    }
  }
  __syncthreads();
  if (tid == 0) {
    int acc = 0;
    for (int e = 0; e < NEXP; ++e) {
      counts[e]  = scnt[e];
      offsets[e] = acc;
      soff[e]    = acc;
      acc += ((scnt[e] + 127) >> 7) << 7;
    }
  }
  __syncthreads();
  for (int i = tid; i < 2 * T_TOK; i += 256) {
    int v = pos_map[i];
    if (v >= 0) pos_map[i] = soff[v & 7] + (v >> 3);
  }
}

// ---------------- hidden_states f32 -> bf16 ----------------
__global__ void cvt_x_kernel(const float* __restrict__ x, unsigned short* __restrict__ xb) {
  int i = blockIdx.x * 256 + threadIdx.x;
  float4 v = ((const float4*)x)[i];
  u16x4 o;
  o[0] = f32_to_bf16(v.x); o[1] = f32_to_bf16(v.y);
  o[2] = f32_to_bf16(v.z); o[3] = f32_to_bf16(v.w);
  *((u16x4*)(xb + 4 * (size_t)i)) = o;
}

// ---------------- GEMM1: h = gelu_tanh(X Wg^T) * (X Wu^T) ----------------
// BK=32, 2-deep B-register pipeline, counted vmcnt(4), 3D grid (natural XCD panel locality).
#define G1_STEP(CUR, NXT, TILE, CG0, CG1, CU0, CU1, LG0, LG1, LU0, LU1)                            \
  {                                                                                                \
    WAIT_VM4(); SCHED_FENCE();                                                                     \
    __builtin_amdgcn_s_barrier(); SCHED_FENCE();                                                   \
    {                                                                                              \
      int ka_ = ((TILE) + 1) * 32; if (ka_ >= HID) ka_ = 0;                                        \
      char* base_ = (char*)&As[NXT][0][0][0];                                                      \
      gload_lds16(asrc + ka_ + akg * 8,       base_ + (size_t)tid * 16);                           \
      gload_lds16(asrc + ka_ + (akg + 2) * 8, base_ + 4096 + (size_t)tid * 16);                    \
    }                                                                                              \
    SCHED_FENCE();                                                                                 \
    {                                                                                              \
      int kb_ = ((TILE) + 2) * 32; if (kb_ >= HID) kb_ = 0;                                        \
      const float4* gp_ = (const float4*)(gsrc + kb_);                                             \
      const float4* up_ = (const float4*)(usrc + kb_);                                             \
      LG0 = gp_[0]; LG1 = gp_[1]; LU0 = up_[0]; LU1 = up_[1];                                      \
    }                                                                                              \
    SCHED_FENCE();                                                                                 \
    {                                                                                              \
      int kg_ = lane >> 4;                                                                         \
      int rl_ = lane & 15;                                                                         \
      bf16x8 af[4], gf[2], uf[2];                                                                  \
      for (int m = 0; m < 4; ++m)                                                                  \
        af[m] = *((const bf16x8*)&As[CUR][kg_][wm * 64 + m * 16 + rl_][0]);                        \
      for (int n = 0; n < 2; ++n) {                                                                \
        int r_ = (wn * 32 + n * 16 + rl_) ^ kg_;                                                   \
        gf[n] = *((const bf16x8*)&Gs[CUR][kg_][r_][0]);                                            \
        uf[n] = *((const bf16x8*)&Us[CUR][kg_][r_][0]);                                            \
      }                                                                                            \
      __builtin_amdgcn_s_setprio(1);                                                               \
      for (int m = 0; m < 4; ++m)                                                                  \
        for (int n = 0; n < 2; ++n) {                                                              \
          accg[m][n] = __builtin_amdgcn_mfma_f32_16x16x32_bf16(af[m], gf[n], accg[m][n], 0, 0, 0); \
          accu[m][n] = __builtin_amdgcn_mfma_f32_16x16x32_bf16(af[m], uf[n], accu[m][n], 0, 0, 0); \
        }                                                                                          \
      __builtin_amdgcn_s_setprio(0);                                                               \
    }                                                                                              \
    *((u16x8*)&Gs[NXT][bq][brw][0]) = cvt8(CG0, CG1);                                              \
    *((u16x8*)&Us[NXT][bq][brw][0]) = cvt8(CU0, CU1);                                              \
    WAIT_LGKM0(); SCHED_FENCE();                                                                   \
  }

__global__ __launch_bounds__(256, 3)
void gemm1_kernel(const unsigned short* __restrict__ xb,
                  const float* __restrict__ gup,
                  const int* __restrict__ counts,
                  const int* __restrict__ offsets,
                  const int* __restrict__ tok_list,
                  unsigned short* __restrict__ hbuf) {
  int e  = blockIdx.z;
  int Ne = counts[e];
  int m0 = blockIdx.y * 128;   // y-step keeps lid%8 fixed -> same XCD shares the n-panel
  if (m0 >= Ne) return;
  int n0  = blockIdx.x * 64;
  int off = offsets[e];

  __shared__ __align__(16) unsigned short As[2][4][128][8];  // 16 KB
  __shared__ __align__(16) unsigned short Gs[2][4][64][8];   // 8 KB
  __shared__ __align__(16) unsigned short Us[2][4][64][8];   // 8 KB

  int tid  = threadIdx.x;
  int lane = tid & 63;
  int wave = tid >> 6;
  int wm = wave >> 1;
  int wn = wave & 1;

  int arow = tid & 127;
  int akg  = tid >> 7;          // 0/1
  int rg   = m0 + arow;
  int tok  = (rg < Ne) ? tok_list[e * T_TOK + rg] : 0;
  const unsigned short* asrc = xb + (size_t)tok * HID;

  int brow = tid >> 2;
  int bq   = tid & 3;           // k-group 0..3
  const float* gsrc = gup + (size_t)e * (2 * INTERN) * HID + (size_t)(n0 + brow) * HID + bq * 8;
  const float* usrc = gsrc + (size_t)INTERN * HID;
  int brw = brow ^ bq;          // XOR-swizzled write row

  f32x4 accg[4][2], accu[4][2];
#pragma unroll
  for (int m = 0; m < 4; ++m)
#pragma unroll
    for (int n = 0; n < 2; ++n) {
      accg[m][n] = (f32x4){0.f, 0.f, 0.f, 0.f};
      accu[m][n] = (f32x4){0.f, 0.f, 0.f, 0.f};
    }

  float4 xg0, xg1, xu0, xu1;   // B-reg set X
  float4 yg0, yg1, yu0, yu1;   // B-reg set Y

  // ---- prologue ----
  {
    char* base = (char*)&As[0][0][0][0];
    gload_lds16(asrc + akg * 8,       base + (size_t)tid * 16);
    gload_lds16(asrc + (akg + 2) * 8, base + 4096 + (size_t)tid * 16);
    // B(0) -> LDS buf0 (serial, once)
    const float4* gp = (const float4*)gsrc;
    const float4* up = (const float4*)usrc;
    float4 tg0 = gp[0], tg1 = gp[1], tu0 = up[0], tu1 = up[1];
    *((u16x8*)&Gs[0][bq][brw][0]) = cvt8(tg0, tg1);
    *((u16x8*)&Us[0][bq][brw][0]) = cvt8(tu0, tu1);
    // B(1) -> set Y (consumed at t=0)
    const float4* gp1 = (const float4*)(gsrc + 32);
    const float4* up1 = (const float4*)(usrc + 32);
    yg0 = gp1[0]; yg1 = gp1[1]; yu0 = up1[0]; yu1 = up1[1];
    WAIT_LGKM0();
    WAIT_VM0();   // A(0) DMA must be in LDS before iter-0 compute (vm4 won't drain it)
    SCHED_FENCE();
  }

  const int NT = HID / 32;   // 32 (even)
  for (int tt = 0; tt < NT; tt += 2) {
    G1_STEP(0, 1, tt,     yg0, yg1, yu0, yu1,  xg0, xg1, xu0, xu1);
    G1_STEP(1, 0, tt + 1, xg0, xg1, xu0, xu1,  yg0, yg1, yu0, yu1);
  }
  WAIT_VM0();   // drain dummy prefetches

  int rl = lane & 15;
  int rq = lane >> 4;
  size_t hb_base = (size_t)((off + m0) >> 7) * (INTERN * 128);
#pragma unroll
  for (int m = 0; m < 4; ++m) {
#pragma unroll
    for (int n = 0; n < 2; ++n) {
      int col = n0 + wn * 32 + n * 16 + rl;
      size_t cbase = hb_base + (size_t)(col >> 3) * 1024 + (col & 7);
#pragma unroll
      for (int j = 0; j < 4; ++j) {
        int lr = wm * 64 + m * 16 + rq * 4 + j;
        if (m0 + lr < Ne) {
          float gv = accg[m][n][j];
          float uv = accu[m][n][j];
          float tt2 = gv + 0.044715f * gv * gv * gv;
          float a  = gv / (1.0f + __expf(-1.5957691216f * tt2));  // == gelu_pytorch_tanh
          hbuf[cbase + (size_t)lr * 8] = f32_to_bf16(a * uv);
        }
      }
    }
  }
}

// ---------------- GEMM2: y = h Wd^T (blocked-A, BK=64, 2-deep B pipeline) ----------------
#define G2_STEP(CUR, NXT, TILE, CB0, CB1, CB2, CB3, LB0, LB1, LB2, LB3)                            \
  {                                                                                                \
    WAIT_VM4(); SCHED_FENCE();                                                                     \
    __builtin_amdgcn_s_barrier(); SCHED_FENCE();                                                   \
    {                                                                                              \
      int ka_ = ((TILE) + 1) * 64; if (ka_ >= INTERN) ka_ = 0;                                     \
      char* base_ = (char*)&As[NXT][0][0][0];                                                      \
      const unsigned short* ak_ = asrc + (size_t)ka_ * 128;                                        \
      for (int o = 0; o < 4; ++o)                                                                  \
        gload_lds16(ak_ + o * 2048 + (size_t)tid * 8, base_ + o * 4096 + (size_t)tid * 16);        \
    }                                                                                              \
    SCHED_FENCE();                                                                                 \
    {                                                                                              \
      int kb_ = ((TILE) + 2) * 64; if (kb_ >= INTERN) kb_ = 0;                                     \
      const float4* bp_ = (const float4*)(bsrc + kb_);                                             \
      LB0 = bp_[0]; LB1 = bp_[1]; LB2 = bp_[2]; LB3 = bp_[3];                                      \
    }                                                                                              \
    SCHED_FENCE();                                                                                 \
    for (int kk = 0; kk < 2; ++kk) {                                                               \
      int kg_ = kk * 4 + (lane >> 4);                                                              \
      int rl_ = lane & 15;                                                                         \
      bf16x8 af[4], bfv[2];                                                                        \
      for (int m = 0; m < 4; ++m)                                                                  \
        af[m] = *((const bf16x8*)&As[CUR][kg_][wm * 64 + m * 16 + rl_][0]);                        \
      for (int n = 0; n < 2; ++n)                                                                  \
        bfv[n] = *((const bf16x8*)&Bs[CUR][kg_][(wn * 32 + n * 16 + rl_) ^ kg_][0]);               \
      __builtin_amdgcn_s_setprio(1);                                                               \
      for (int m = 0; m < 4; ++m)                                                                  \
        for (int n = 0; n < 2; ++n)                                                                \
          acc[m][n] = __builtin_amdgcn_mfma_f32_16x16x32_bf16(af[m], bfv[n], acc[m][n], 0, 0, 0);  \
      __builtin_amdgcn_s_setprio(0);                                                               \
    }                                                                                              \
    *((u16x8*)&Bs[NXT][kgw0][brow ^ kgw0][0]) = cvt8(CB0, CB1);                                    \
    *((u16x8*)&Bs[NXT][kgw1][brow ^ kgw1][0]) = cvt8(CB2, CB3);                                    \
    WAIT_LGKM0(); SCHED_FENCE();                                                                   \
  }

__global__ __launch_bounds__(256, 2)
void gemm2_kernel(const unsigned short* __restrict__ hbuf,
                  const float* __restrict__ down,
                  const int* __restrict__ counts,
                  const int* __restrict__ offsets,
                  unsigned short* __restrict__ ybuf) {
  int e  = blockIdx.z;
  int Ne = counts[e];
  int m0 = blockIdx.y * 128;
  if (m0 >= Ne) return;
  int n0  = blockIdx.x * 64;
  int off = offsets[e];

  __shared__ __align__(16) unsigned short As[2][8][128][8];  // 32 KB
  __shared__ __align__(16) unsigned short Bs[2][8][64][8];   // 16 KB

  int tid  = threadIdx.x;
  int lane = tid & 63;
  int wave = tid >> 6;
  int wm = wave >> 1;
  int wn = wave & 1;

  const unsigned short* asrc = hbuf + (size_t)((off + m0) >> 7) * (INTERN * 128);

  int brow = tid >> 2;
  int bq   = tid & 3;
  int kgw0 = bq * 2, kgw1 = bq * 2 + 1;
  const float* bsrc = down + (size_t)e * HID * INTERN + (size_t)(n0 + brow) * INTERN + bq * 16;

  f32x4 acc[4][2];
#pragma unroll
  for (int m = 0; m < 4; ++m)
#pragma unroll
    for (int n = 0; n < 2; ++n) acc[m][n] = (f32x4){0.f, 0.f, 0.f, 0.f};

  float4 xb0, xb1, xb2, xb3;   // B-reg set X
  float4 yb0, yb1, yb2, yb3;   // B-reg set Y

  // ---- prologue ----
  {
    char* base = (char*)&As[0][0][0][0];
#pragma unroll
    for (int o = 0; o < 4; ++o)
      gload_lds16(asrc + o * 2048 + (size_t)tid * 8, base + o * 4096 + (size_t)tid * 16);
    const float4* bp = (const float4*)bsrc;
    float4 t0 = bp[0], t1 = bp[1], t2 = bp[2], t3 = bp[3];
    *((u16x8*)&Bs[0][kgw0][brow ^ kgw0][0]) = cvt8(t0, t1);
    *((u16x8*)&Bs[0][kgw1][brow ^ kgw1][0]) = cvt8(t2, t3);
    const float4* bp1 = (const float4*)(bsrc + 64);
    yb0 = bp1[0]; yb1 = bp1[1]; yb2 = bp1[2]; yb3 = bp1[3];
    WAIT_LGKM0();
    WAIT_VM0();   // A(0) DMA must be in LDS before iter-0 compute
    SCHED_FENCE();
  }

  const int NT = INTERN / 64;   // 32 (even)
  for (int tt = 0; tt < NT; tt += 2) {
    G2_STEP(0, 1, tt,     yb0, yb1, yb2, yb3,  xb0, xb1, xb2, xb3);
    G2_STEP(1, 0, tt + 1, xb0, xb1, xb2, xb3,  yb0, yb1, yb2, yb3);
  }
  WAIT_VM0();

  int rl = lane & 15;
  int rq = lane >> 4;
#pragma unroll
  for (int m = 0; m < 4; ++m) {
#pragma unroll
    for (int n = 0; n < 2; ++n) {
      int col = n0 + wn * 32 + n * 16 + rl;
#pragma unroll
      for (int j = 0; j < 4; ++j) {
        int lr = wm * 64 + m * 16 + rq * 4 + j;
        if (m0 + lr < Ne)
          ybuf[(size_t)(off + m0 + lr) * HID + col] = f32_to_bf16(acc[m][n][j]);
      }
    }
  }
}

// ---------------- final combine ----------------
__global__ void combine_kernel(const int* __restrict__ pos_map,
                               const float* __restrict__ wgt_map,
                               const unsigned short* __restrict__ ybuf,
                               float* __restrict__ out) {
  int i  = blockIdx.x * 256 + threadIdx.x;
  int t  = i >> 7;
  int c8 = i & 127;
  int p0 = pos_map[2 * t];
  int p1 = pos_map[2 * t + 1];
  float w0 = wgt_map[2 * t];
  float w1 = wgt_map[2 * t + 1];
  float acc[8];
#pragma unroll
  for (int j = 0; j < 8; ++j) acc[j] = 0.f;
  if (p0 >= 0) {
    u16x8 v = *((const u16x8*)(ybuf + (size_t)p0 * HID + c8 * 8));
#pragma unroll
    for (int j = 0; j < 8; ++j) acc[j] += w0 * bf16_to_f32(v[j]);
  }
  if (p1 >= 0) {
    u16x8 v = *((const u16x8*)(ybuf + (size_t)p1 * HID + c8 * 8));
#pragma unroll
    for (int j = 0; j < 8; ++j) acc[j] += w1 * bf16_to_f32(v[j]);
  }
  float4 o0 = make_float4(acc[0], acc[1], acc[2], acc[3]);
  float4 o1 = make_float4(acc[4], acc[5], acc[6], acc[7]);
  float4* dst = (float4*)(out + (size_t)t * HID + c8 * 8);
  dst[0] = o0;
  dst[1] = o1;
}

// ---------------- launch ----------------
extern "C" void kernel_launch(void* const* d_in, const int* in_sizes, int n_in,
                              void* d_out, int out_size, void* d_ws, size_t ws_size,
                              hipStream_t stream) {
  (void)in_sizes; (void)n_in; (void)out_size;
  const float* hidden = (const float*)d_in[0];
  const int*   tki    = (const int*)d_in[1];
  const float* tkw    = (const float*)d_in[2];
  const float* gup    = (const float*)d_in[3];
  const float* down   = (const float*)d_in[4];
  float* out = (float*)d_out;
  char*  ws  = (char*)d_ws;

  int*   counts   = (int*)  (ws + 0);
  int*   offsets  = (int*)  (ws + 64);
  int*   tok_list = (int*)  (ws + 256);
  int*   pos_map  = (int*)  (ws + 65792);
  float* wgt_map  = (float*)(ws + 82176);
  float* w_list   = (float*)(ws + 98560);
  unsigned short* xb   = (unsigned short*)(ws + 164096);
  unsigned short* hbuf = (unsigned short*)(ws + 4358400);
  unsigned short* ybuf = (unsigned short*)(ws + 25854208);

  if (ws_size < 36602112ull) return;

  hipLaunchKernelGGL(route_kernel, dim3(1), dim3(256), 0, stream,
                     tki, tkw, counts, offsets, tok_list, w_list, pos_map, wgt_map);
  hipLaunchKernelGGL(cvt_x_kernel, dim3((T_TOK * HID / 4) / 256), dim3(256), 0, stream,
                     hidden, xb);
  hipLaunchKernelGGL(gemm1_kernel, dim3(INTERN / 64, T_TOK / 128, NEXP), dim3(256), 0, stream,
                     xb, gup, counts, offsets, tok_list, hbuf);
  hipLaunchKernelGGL(gemm2_kernel, dim3(HID / 64, T_TOK / 128, NEXP), dim3(256), 0, stream,
                     hbuf, down, counts, offsets, ybuf);
  hipLaunchKernelGGL(combine_kernel, dim3(T_TOK * HID / 8 / 256), dim3(256), 0, stream,
                     pos_map, wgt_map, ybuf, out);
}

// Round 9
// 148.541 us; speedup vs baseline: 1.1217x; 1.1217x over previous
//
#include <hip/hip_runtime.h>
#include <stdint.h>

#define T_TOK  2048
#define HID    1024
#define INTERN 2048
#define NEXP   8
#define MAXPOS 5248   // max 128-aligned routed rows (41 blocks of 128)

typedef __attribute__((ext_vector_type(8))) short          bf16x8;
typedef __attribute__((ext_vector_type(4))) float          f32x4;
typedef __attribute__((ext_vector_type(8))) unsigned short u16x8;
typedef __attribute__((ext_vector_type(4))) unsigned short u16x4;

__device__ __forceinline__ unsigned short f32_to_bf16(float f) {
  unsigned int u = __float_as_uint(f);
  unsigned int r = (u + 0x7FFFu + ((u >> 16) & 1u)) >> 16;
  return (unsigned short)r;
}

__device__ __forceinline__ float bf16_to_f32(unsigned short h) {
  unsigned int u = ((unsigned int)h) << 16;
  return __uint_as_float(u);
}

__device__ __forceinline__ void gload_lds16(const void* g, void* l) {
  __builtin_amdgcn_global_load_lds(
      (const __attribute__((address_space(1))) unsigned int*)g,
      (__attribute__((address_space(3))) unsigned int*)l, 16, 0, 0);
}

__device__ __forceinline__ u16x8 cvt8(float4 a, float4 b) {
  u16x8 w;
  w[0] = f32_to_bf16(a.x); w[1] = f32_to_bf16(a.y);
  w[2] = f32_to_bf16(a.z); w[3] = f32_to_bf16(a.w);
  w[4] = f32_to_bf16(b.x); w[5] = f32_to_bf16(b.y);
  w[6] = f32_to_bf16(b.z); w[7] = f32_to_bf16(b.w);
  return w;
}

#define WAIT_VM0()    asm volatile("s_waitcnt vmcnt(0)" ::: "memory")
#define WAIT_LGKM0()  asm volatile("s_waitcnt lgkmcnt(0)" ::: "memory")
#define SCHED_FENCE() __builtin_amdgcn_sched_barrier(0)

// ---------------- routing ----------------
__global__ void route_kernel(const int* __restrict__ tki,
                             const float* __restrict__ tkw,
                             int* __restrict__ counts,
                             int* __restrict__ offsets,
                             int* __restrict__ tok_list,
                             float* __restrict__ w_list,
                             int* __restrict__ pos_map,
                             float* __restrict__ wgt_map) {
  __shared__ int scnt[NEXP];
  __shared__ int soff[NEXP];
  int tid = threadIdx.x;
  if (tid < NEXP) scnt[tid] = 0;
  __syncthreads();
  for (int t = tid; t < T_TOK; t += 256) {
    int e0 = tki[2 * t] & 7;
    int e1 = tki[2 * t + 1] & 7;
    float w0 = tkw[2 * t];
    float w1 = tkw[2 * t + 1];
    if (e0 == e1) {
      int p = atomicAdd(&scnt[e0], 1);
      tok_list[e0 * T_TOK + p] = t;
      w_list [e0 * T_TOK + p] = w0 + w1;
      pos_map[2 * t]     = (p << 3) | e0;
      wgt_map[2 * t]     = w0 + w1;
      pos_map[2 * t + 1] = -1;
      wgt_map[2 * t + 1] = 0.0f;
    } else {
      int p = atomicAdd(&scnt[e0], 1);
      tok_list[e0 * T_TOK + p] = t;
      w_list [e0 * T_TOK + p] = w0;
      pos_map[2 * t]     = (p << 3) | e0;
      wgt_map[2 * t]     = w0;
      int q = atomicAdd(&scnt[e1], 1);
      tok_list[e1 * T_TOK + q] = t;
      w_list [e1 * T_TOK + q] = w1;
      pos_map[2 * t + 1] = (q << 3) | e1;
      wgt_map[2 * t + 1] = w1;
    }
  }
  __syncthreads();
  if (tid == 0) {
    int acc = 0;
    for (int e = 0; e < NEXP; ++e) {
      counts[e]  = scnt[e];
      offsets[e] = acc;
      soff[e]    = acc;
      acc += ((scnt[e] + 127) >> 7) << 7;
    }
  }
  __syncthreads();
  for (int i = tid; i < 2 * T_TOK; i += 256) {
    int v = pos_map[i];
    if (v >= 0) pos_map[i] = soff[v & 7] + (v >> 3);
  }
}

// ---------------- hidden_states f32 -> bf16 (row-major) ----------------
__global__ void cvt_x_kernel(const float* __restrict__ x, unsigned short* __restrict__ xb) {
  int i = blockIdx.x * 256 + threadIdx.x;
  float4 v = ((const float4*)x)[i];
  u16x4 o;
  o[0] = f32_to_bf16(v.x); o[1] = f32_to_bf16(v.y);
  o[2] = f32_to_bf16(v.z); o[3] = f32_to_bf16(v.w);
  *((u16x4*)(xb + 4 * (size_t)i)) = o;
}

// ---------------- gather X into per-expert BLOCKED layout ----------------
// xg[(p>>7)*131072 + c*1024 + (p&127)*8 .. +8] = xb[tok(p)*1024 + c*8 .. +8]
// block: 128 threads (rows p of one 128-chunk), blockIdx.x = chunk, blockIdx.y = c.
__global__ void gather_x_kernel(const unsigned short* __restrict__ xb,
                                const int* __restrict__ counts,
                                const int* __restrict__ offsets,
                                const int* __restrict__ tok_list,
                                unsigned short* __restrict__ xg) {
  int p = blockIdx.x * 128 + threadIdx.x;
  int c = blockIdx.y;           // 0..127, 8-elem group
  int e = 0;
#pragma unroll
  for (int k = 1; k < NEXP; ++k) if (p >= offsets[k]) e = k;
  int r = p - offsets[e];
  u16x8 v = (u16x8){0, 0, 0, 0, 0, 0, 0, 0};
  if (r < counts[e]) {
    int tok = tok_list[e * T_TOK + r];
    v = *((const u16x8*)(xb + (size_t)tok * HID + c * 8));
  }
  *((u16x8*)(xg + (size_t)(p >> 7) * 131072 + c * 1024 + (p & 127) * 8)) = v;
}

// ---------------- GEMM1: h = gelu_tanh(X Wg^T) * (X Wu^T) ----------------
// BK=32, round-6 schedule (vmcnt0 + single barrier), LINEAR A-DMA from blocked xg.
__global__ __launch_bounds__(256, 4)
void gemm1_kernel(const unsigned short* __restrict__ xg,
                  const float* __restrict__ gup,
                  const int* __restrict__ counts,
                  const int* __restrict__ offsets,
                  unsigned short* __restrict__ hbuf) {
  int e  = blockIdx.z;
  int Ne = counts[e];
  int m0 = blockIdx.y * 128;
  if (m0 >= Ne) return;
  int n0  = blockIdx.x * 64;
  int off = offsets[e];

  __shared__ __align__(16) unsigned short As[2][4][128][8];  // 16 KB
  __shared__ __align__(16) unsigned short Gs[2][4][64][8];   // 8 KB
  __shared__ __align__(16) unsigned short Us[2][4][64][8];   // 8 KB

  int tid  = threadIdx.x;
  int lane = tid & 63;
  int wave = tid >> 6;
  int wm = wave >> 1;
  int wn = wave & 1;

  // A staging: blocked xg -> fully linear DMA
  const unsigned short* asrc = xg + (size_t)((off + m0) >> 7) * (HID * 128);

  int brow = tid >> 2;
  int bq   = tid & 3;           // k-group 0..3
  const float* gsrc = gup + (size_t)e * (2 * INTERN) * HID + (size_t)(n0 + brow) * HID + bq * 8;
  const float* usrc = gsrc + (size_t)INTERN * HID;
  int brw = brow ^ bq;          // XOR-swizzled write row

  f32x4 accg[4][2], accu[4][2];
#pragma unroll
  for (int m = 0; m < 4; ++m)
#pragma unroll
    for (int n = 0; n < 2; ++n) {
      accg[m][n] = (f32x4){0.f, 0.f, 0.f, 0.f};
      accu[m][n] = (f32x4){0.f, 0.f, 0.f, 0.f};
    }

  float4 g0, g1, u0, u1;

  // ---- prologue: tile 0 ----
  {
    const float4* gp = (const float4*)gsrc;
    const float4* up = (const float4*)usrc;
    g0 = gp[0]; g1 = gp[1];
    u0 = up[0]; u1 = up[1];
    char* base = (char*)&As[0][0][0][0];
    gload_lds16(asrc + (size_t)tid * 8,        base + (size_t)tid * 16);
    gload_lds16(asrc + 2048 + (size_t)tid * 8, base + 4096 + (size_t)tid * 16);
    *((u16x8*)&Gs[0][bq][brw][0]) = cvt8(g0, g1);
    *((u16x8*)&Us[0][bq][brw][0]) = cvt8(u0, u1);
    WAIT_LGKM0(); SCHED_FENCE();
  }

  int cur = 0;
  const int NT = HID / 32;   // 32
  for (int t = 0; t < NT; ++t) {
    WAIT_VM0(); SCHED_FENCE();          // A-DMA(t) landed
    __builtin_amdgcn_s_barrier(); SCHED_FENCE();
    int nxt = cur ^ 1;
    int kn = (t + 1 < NT) ? (t + 1) * 32 : 0;   // wrapped dummy prefetch on last iter
    // issue next B loads (registers; consumed after MFMA)
    {
      const float4* gp = (const float4*)(gsrc + kn);
      const float4* up = (const float4*)(usrc + kn);
      g0 = gp[0]; g1 = gp[1];
      u0 = up[0]; u1 = up[1];
    }
    // issue next A DMA (linear, blocked xg)
    {
      char* base = (char*)&As[nxt][0][0][0];
      const unsigned short* ak = asrc + (size_t)kn * 128;
      gload_lds16(ak + (size_t)tid * 8,        base + (size_t)tid * 16);
      gload_lds16(ak + 2048 + (size_t)tid * 8, base + 4096 + (size_t)tid * 16);
    }
    SCHED_FENCE();                       // issues stay above compute
    // compute current tile (16 MFMA)
    {
      int kg = lane >> 4;
      int rl = lane & 15;
      bf16x8 af[4], gf[2], uf[2];
#pragma unroll
      for (int m = 0; m < 4; ++m)
        af[m] = *((const bf16x8*)&As[cur][kg][wm * 64 + m * 16 + rl][0]);
#pragma unroll
      for (int n = 0; n < 2; ++n) {
        int r = (wn * 32 + n * 16 + rl) ^ kg;
        gf[n] = *((const bf16x8*)&Gs[cur][kg][r][0]);
        uf[n] = *((const bf16x8*)&Us[cur][kg][r][0]);
      }
#pragma unroll
      for (int m = 0; m < 4; ++m)
#pragma unroll
        for (int n = 0; n < 2; ++n) {
          accg[m][n] = __builtin_amdgcn_mfma_f32_16x16x32_bf16(af[m], gf[n], accg[m][n], 0, 0, 0);
          accu[m][n] = __builtin_amdgcn_mfma_f32_16x16x32_bf16(af[m], uf[n], accu[m][n], 0, 0, 0);
        }
    }
    // stage next B into LDS (compiler inserts exact vmcnt for register deps)
    *((u16x8*)&Gs[nxt][bq][brw][0]) = cvt8(g0, g1);
    *((u16x8*)&Us[nxt][bq][brw][0]) = cvt8(u0, u1);
    WAIT_LGKM0(); SCHED_FENCE();         // ds_writes visible before next barrier
    cur = nxt;
  }
  WAIT_VM0();                            // drain dummy prefetch

  int rl = lane & 15;
  int rq = lane >> 4;
  size_t hb_base = (size_t)((off + m0) >> 7) * (INTERN * 128);
#pragma unroll
  for (int m = 0; m < 4; ++m) {
#pragma unroll
    for (int n = 0; n < 2; ++n) {
      int col = n0 + wn * 32 + n * 16 + rl;
      size_t cbase = hb_base + (size_t)(col >> 3) * 1024 + (col & 7);
#pragma unroll
      for (int j = 0; j < 4; ++j) {
        int lr = wm * 64 + m * 16 + rq * 4 + j;
        if (m0 + lr < Ne) {
          float gv = accg[m][n][j];
          float uv = accu[m][n][j];
          float tt2 = gv + 0.044715f * gv * gv * gv;
          float a  = gv / (1.0f + __expf(-1.5957691216f * tt2));  // == gelu_pytorch_tanh
          hbuf[cbase + (size_t)lr * 8] = f32_to_bf16(a * uv);
        }
      }
    }
  }
}

// ---------------- GEMM2: y = h Wd^T (blocked-A, BK=64, round-5 schedule) ----------------
__global__ __launch_bounds__(256, 2)
void gemm2_kernel(const unsigned short* __restrict__ hbuf,
                  const float* __restrict__ down,
                  const int* __restrict__ counts,
                  const int* __restrict__ offsets,
                  unsigned short* __restrict__ ybuf) {
  int e  = blockIdx.z;
  int Ne = counts[e];
  int m0 = blockIdx.y * 128;
  if (m0 >= Ne) return;
  int n0  = blockIdx.x * 64;
  int off = offsets[e];

  __shared__ __align__(16) unsigned short As[2][8][128][8];  // 32 KB
  __shared__ __align__(16) unsigned short Bs[2][8][64][8];   // 16 KB

  int tid  = threadIdx.x;
  int lane = tid & 63;
  int wave = tid >> 6;
  int wm = wave >> 1;
  int wn = wave & 1;

  const unsigned short* asrc = hbuf + (size_t)((off + m0) >> 7) * (INTERN * 128);

  int brow = tid >> 2;
  int bq   = tid & 3;
  int kgw0 = bq * 2, kgw1 = bq * 2 + 1;
  const float* bsrc = down + (size_t)e * HID * INTERN + (size_t)(n0 + brow) * INTERN + bq * 16;

  f32x4 acc[4][2];
#pragma unroll
  for (int m = 0; m < 4; ++m)
#pragma unroll
    for (int n = 0; n < 2; ++n) acc[m][n] = (f32x4){0.f, 0.f, 0.f, 0.f};

  float4 b0, b1, b2, b3;

  // ---- prologue: tile 0 ----
  {
    const float4* bp = (const float4*)bsrc;
    b0 = bp[0]; b1 = bp[1]; b2 = bp[2]; b3 = bp[3];
    char* base = (char*)&As[0][0][0][0];
#pragma unroll
    for (int o = 0; o < 4; ++o)
      gload_lds16(asrc + o * 2048 + (size_t)tid * 8, base + o * 4096 + (size_t)tid * 16);
    *((u16x8*)&Bs[0][kgw0][brow ^ kgw0][0]) = cvt8(b0, b1);
    *((u16x8*)&Bs[0][kgw1][brow ^ kgw1][0]) = cvt8(b2, b3);
    WAIT_LGKM0(); SCHED_FENCE();
  }

  int cur = 0;
  const int NT = INTERN / 64;   // 32
  for (int t = 0; t < NT; ++t) {
    WAIT_VM0(); SCHED_FENCE();
    __builtin_amdgcn_s_barrier(); SCHED_FENCE();
    int nxt = cur ^ 1;
    int kn = (t + 1 < NT) ? (t + 1) * 64 : 0;
    // issue next B loads
    {
      const float4* bp = (const float4*)(bsrc + kn);
      b0 = bp[0]; b1 = bp[1]; b2 = bp[2]; b3 = bp[3];
    }
    // issue next A DMA (fully linear: blocked hbuf layout)
    {
      char* base = (char*)&As[nxt][0][0][0];
      const unsigned short* ak = asrc + (size_t)kn * 128;
#pragma unroll
      for (int o = 0; o < 4; ++o)
        gload_lds16(ak + o * 2048 + (size_t)tid * 8, base + o * 4096 + (size_t)tid * 16);
    }
    SCHED_FENCE();
    // compute current tile
#pragma unroll
    for (int kk = 0; kk < 2; ++kk) {
      int kg = kk * 4 + (lane >> 4);
      int rl = lane & 15;
      bf16x8 af[4], bfv[2];
#pragma unroll
      for (int m = 0; m < 4; ++m)
        af[m] = *((const bf16x8*)&As[cur][kg][wm * 64 + m * 16 + rl][0]);
#pragma unroll
      for (int n = 0; n < 2; ++n)
        bfv[n] = *((const bf16x8*)&Bs[cur][kg][(wn * 32 + n * 16 + rl) ^ kg][0]);
#pragma unroll
      for (int m = 0; m < 4; ++m)
#pragma unroll
        for (int n = 0; n < 2; ++n)
          acc[m][n] = __builtin_amdgcn_mfma_f32_16x16x32_bf16(af[m], bfv[n], acc[m][n], 0, 0, 0);
    }
    // stage next B
    *((u16x8*)&Bs[nxt][kgw0][brow ^ kgw0][0]) = cvt8(b0, b1);
    *((u16x8*)&Bs[nxt][kgw1][brow ^ kgw1][0]) = cvt8(b2, b3);
    WAIT_LGKM0(); SCHED_FENCE();
    cur = nxt;
  }
  WAIT_VM0();

  int rl = lane & 15;
  int rq = lane >> 4;
#pragma unroll
  for (int m = 0; m < 4; ++m) {
#pragma unroll
    for (int n = 0; n < 2; ++n) {
      int col = n0 + wn * 32 + n * 16 + rl;
#pragma unroll
      for (int j = 0; j < 4; ++j) {
        int lr = wm * 64 + m * 16 + rq * 4 + j;
        if (m0 + lr < Ne)
          ybuf[(size_t)(off + m0 + lr) * HID + col] = f32_to_bf16(acc[m][n][j]);
      }
    }
  }
}

// ---------------- final combine ----------------
__global__ void combine_kernel(const int* __restrict__ pos_map,
                               const float* __restrict__ wgt_map,
                               const unsigned short* __restrict__ ybuf,
                               float* __restrict__ out) {
  int i  = blockIdx.x * 256 + threadIdx.x;
  int t  = i >> 7;
  int c8 = i & 127;
  int p0 = pos_map[2 * t];
  int p1 = pos_map[2 * t + 1];
  float w0 = wgt_map[2 * t];
  float w1 = wgt_map[2 * t + 1];
  float acc[8];
#pragma unroll
  for (int j = 0; j < 8; ++j) acc[j] = 0.f;
  if (p0 >= 0) {
    u16x8 v = *((const u16x8*)(ybuf + (size_t)p0 * HID + c8 * 8));
#pragma unroll
    for (int j = 0; j < 8; ++j) acc[j] += w0 * bf16_to_f32(v[j]);
  }
  if (p1 >= 0) {
    u16x8 v = *((const u16x8*)(ybuf + (size_t)p1 * HID + c8 * 8));
#pragma unroll
    for (int j = 0; j < 8; ++j) acc[j] += w1 * bf16_to_f32(v[j]);
  }
  float4 o0 = make_float4(acc[0], acc[1], acc[2], acc[3]);
  float4 o1 = make_float4(acc[4], acc[5], acc[6], acc[7]);
  float4* dst = (float4*)(out + (size_t)t * HID + c8 * 8);
  dst[0] = o0;
  dst[1] = o1;
}

// ---------------- launch ----------------
extern "C" void kernel_launch(void* const* d_in, const int* in_sizes, int n_in,
                              void* d_out, int out_size, void* d_ws, size_t ws_size,
                              hipStream_t stream) {
  (void)in_sizes; (void)n_in; (void)out_size;
  const float* hidden = (const float*)d_in[0];
  const int*   tki    = (const int*)d_in[1];
  const float* tkw    = (const float*)d_in[2];
  const float* gup    = (const float*)d_in[3];
  const float* down   = (const float*)d_in[4];
  float* out = (float*)d_out;
  char*  ws  = (char*)d_ws;

  int*   counts   = (int*)  (ws + 0);
  int*   offsets  = (int*)  (ws + 64);
  int*   tok_list = (int*)  (ws + 256);
  int*   pos_map  = (int*)  (ws + 65792);
  float* wgt_map  = (float*)(ws + 82176);
  float* w_list   = (float*)(ws + 98560);
  unsigned short* xb   = (unsigned short*)(ws + 164096);    // 2048*1024 bf16
  unsigned short* hbuf = (unsigned short*)(ws + 4358400);   // MAXPOS*2048 bf16 (blocked)
  unsigned short* ybuf = (unsigned short*)(ws + 25854208);  // MAXPOS*1024 bf16
  unsigned short* xg   = ybuf;  // alias: xg dead before gemm2 writes ybuf

  if (ws_size < 36602112ull) return;

  hipLaunchKernelGGL(route_kernel, dim3(1), dim3(256), 0, stream,
                     tki, tkw, counts, offsets, tok_list, w_list, pos_map, wgt_map);
  hipLaunchKernelGGL(cvt_x_kernel, dim3((T_TOK * HID / 4) / 256), dim3(256), 0, stream,
                     hidden, xb);
  hipLaunchKernelGGL(gather_x_kernel, dim3(MAXPOS / 128, 128), dim3(128), 0, stream,
                     xb, counts, offsets, tok_list, xg);
  hipLaunchKernelGGL(gemm1_kernel, dim3(INTERN / 64, T_TOK / 128, NEXP), dim3(256), 0, stream,
                     xg, gup, counts, offsets, hbuf);
  hipLaunchKernelGGL(gemm2_kernel, dim3(HID / 64, T_TOK / 128, NEXP), dim3(256), 0, stream,
                     hbuf, down, counts, offsets, ybuf);
  hipLaunchKernelGGL(combine_kernel, dim3(T_TOK * HID / 8 / 256), dim3(256), 0, stream,
                     pos_map, wgt_map, ybuf, out);
}

// Round 10
// 139.274 us; speedup vs baseline: 1.1964x; 1.0665x over previous
//
#include <hip/hip_runtime.h>
#include <stdint.h>

#define T_TOK  2048
#define HID    1024
#define INTERN 2048
#define NEXP   8
#define MAXPOS 5248   // max 128-aligned routed rows (41 blocks of 128)

typedef __attribute__((ext_vector_type(8))) short          bf16x8;
typedef __attribute__((ext_vector_type(4))) float          f32x4;
typedef __attribute__((ext_vector_type(8))) unsigned short u16x8;
typedef __attribute__((ext_vector_type(4))) unsigned short u16x4;

__device__ __forceinline__ unsigned short f32_to_bf16(float f) {
  unsigned int u = __float_as_uint(f);
  unsigned int r = (u + 0x7FFFu + ((u >> 16) & 1u)) >> 16;
  return (unsigned short)r;
}

__device__ __forceinline__ float bf16_to_f32(unsigned short h) {
  unsigned int u = ((unsigned int)h) << 16;
  return __uint_as_float(u);
}

__device__ __forceinline__ void gload_lds16(const void* g, void* l) {
  __builtin_amdgcn_global_load_lds(
      (const __attribute__((address_space(1))) unsigned int*)g,
      (__attribute__((address_space(3))) unsigned int*)l, 16, 0, 0);
}

// packed f32->bf16 (RTNE) via v_cvt_pk_bf16_f32: 4 inst per 8 elements
__device__ __forceinline__ u16x8 cvt8(float4 a, float4 b) {
  union { u16x8 s; unsigned int u[4]; } r;
  asm("v_cvt_pk_bf16_f32 %0, %1, %2" : "=v"(r.u[0]) : "v"(a.x), "v"(a.y));
  asm("v_cvt_pk_bf16_f32 %0, %1, %2" : "=v"(r.u[1]) : "v"(a.z), "v"(a.w));
  asm("v_cvt_pk_bf16_f32 %0, %1, %2" : "=v"(r.u[2]) : "v"(b.x), "v"(b.y));
  asm("v_cvt_pk_bf16_f32 %0, %1, %2" : "=v"(r.u[3]) : "v"(b.z), "v"(b.w));
  return r.s;
}

#define WAIT_VM0()    asm volatile("s_waitcnt vmcnt(0)" ::: "memory")
#define WAIT_VM4()    asm volatile("s_waitcnt vmcnt(4)" ::: "memory")
#define WAIT_LGKM0()  asm volatile("s_waitcnt lgkmcnt(0)" ::: "memory")
#define SCHED_FENCE() __builtin_amdgcn_sched_barrier(0)

// ---------------- routing ----------------
__global__ void route_kernel(const int* __restrict__ tki,
                             const float* __restrict__ tkw,
                             int* __restrict__ counts,
                             int* __restrict__ offsets,
                             int* __restrict__ tok_list,
                             float* __restrict__ w_list,
                             int* __restrict__ pos_map,
                             float* __restrict__ wgt_map) {
  __shared__ int scnt[NEXP];
  __shared__ int soff[NEXP];
  int tid = threadIdx.x;
  if (tid < NEXP) scnt[tid] = 0;
  __syncthreads();
  for (int t = tid; t < T_TOK; t += 256) {
    int e0 = tki[2 * t] & 7;
    int e1 = tki[2 * t + 1] & 7;
    float w0 = tkw[2 * t];
    float w1 = tkw[2 * t + 1];
    if (e0 == e1) {
      int p = atomicAdd(&scnt[e0], 1);
      tok_list[e0 * T_TOK + p] = t;
      w_list [e0 * T_TOK + p] = w0 + w1;
      pos_map[2 * t]     = (p << 3) | e0;
      wgt_map[2 * t]     = w0 + w1;
      pos_map[2 * t + 1] = -1;
      wgt_map[2 * t + 1] = 0.0f;
    } else {
      int p = atomicAdd(&scnt[e0], 1);
      tok_list[e0 * T_TOK + p] = t;
      w_list [e0 * T_TOK + p] = w0;
      pos_map[2 * t]     = (p << 3) | e0;
      wgt_map[2 * t]     = w0;
      int q = atomicAdd(&scnt[e1], 1);
      tok_list[e1 * T_TOK + q] = t;
      w_list [e1 * T_TOK + q] = w1;
      pos_map[2 * t + 1] = (q << 3) | e1;
      wgt_map[2 * t + 1] = w1;
    }
  }
  __syncthreads();
  if (tid == 0) {
    int acc = 0;
    for (int e = 0; e < NEXP; ++e) {
      counts[e]  = scnt[e];
      offsets[e] = acc;
      soff[e]    = acc;
      acc += ((scnt[e] + 127) >> 7) << 7;
    }
  }
  __syncthreads();
  for (int i = tid; i < 2 * T_TOK; i += 256) {
    int v = pos_map[i];
    if (v >= 0) pos_map[i] = soff[v & 7] + (v >> 3);
  }
}

// ---------------- fused gather + f32->bf16: hidden -> blocked xg ----------------
// xg[(p>>7)*131072 + c*1024 + (p&127)*8 .. +8] = bf16(hidden[tok(p)*1024 + c*8 .. +8])
// lane dim = c -> coalesced READS from hidden; scatter writes are fire-and-forget.
__global__ void gather_cvt_x_kernel(const float* __restrict__ hidden,
                                    const int* __restrict__ counts,
                                    const int* __restrict__ offsets,
                                    const int* __restrict__ tok_list,
                                    unsigned short* __restrict__ xg) {
  int p = blockIdx.x * 2 + (threadIdx.x >> 7);   // routed position
  int c = threadIdx.x & 127;                     // 8-elem column group
  int e = 0;
#pragma unroll
  for (int k = 1; k < NEXP; ++k) if (p >= offsets[k]) e = k;
  int r = p - offsets[e];
  float4 a = {0.f, 0.f, 0.f, 0.f}, b = {0.f, 0.f, 0.f, 0.f};
  if (r < counts[e]) {
    int tok = tok_list[e * T_TOK + r];
    const float4* src = (const float4*)(hidden + (size_t)tok * HID + c * 8);
    a = src[0]; b = src[1];
  }
  *((u16x8*)(xg + (size_t)(p >> 7) * 131072 + c * 1024 + (p & 127) * 8)) = cvt8(a, b);
}

// ---------------- GEMM1: h = gelu_tanh(X Wg^T) * (X Wu^T) ----------------
// BK=32, linear A-DMA from blocked xg, late-B issue + counted vmcnt(4), single B reg set.
__global__ __launch_bounds__(256, 4)
void gemm1_kernel(const unsigned short* __restrict__ xg,
                  const float* __restrict__ gup,
                  const int* __restrict__ counts,
                  const int* __restrict__ offsets,
                  unsigned short* __restrict__ hbuf) {
  int e  = blockIdx.z;
  int Ne = counts[e];
  int m0 = blockIdx.y * 128;
  if (m0 >= Ne) return;
  int n0  = blockIdx.x * 64;
  int off = offsets[e];

  __shared__ __align__(16) unsigned short As[2][4][128][8];  // 16 KB
  __shared__ __align__(16) unsigned short Gs[2][4][64][8];   // 8 KB
  __shared__ __align__(16) unsigned short Us[2][4][64][8];   // 8 KB

  int tid  = threadIdx.x;
  int lane = tid & 63;
  int wave = tid >> 6;
  int wm = wave >> 1;
  int wn = wave & 1;

  const unsigned short* asrc = xg + (size_t)((off + m0) >> 7) * (HID * 128);

  int brow = tid >> 2;
  int bq   = tid & 3;           // k-group 0..3
  const float* gsrc = gup + (size_t)e * (2 * INTERN) * HID + (size_t)(n0 + brow) * HID + bq * 8;
  const float* usrc = gsrc + (size_t)INTERN * HID;
  int brw = brow ^ bq;          // XOR-swizzled write row

  f32x4 accg[4][2], accu[4][2];
#pragma unroll
  for (int m = 0; m < 4; ++m)
#pragma unroll
    for (int n = 0; n < 2; ++n) {
      accg[m][n] = (f32x4){0.f, 0.f, 0.f, 0.f};
      accu[m][n] = (f32x4){0.f, 0.f, 0.f, 0.f};
    }

  float4 g0, g1, u0, u1;   // single in-flight B reg set (holds tile t+1)

  // ---- prologue: A(0) DMA; B(0)->LDS0; issue B(1) ----
  {
    char* base = (char*)&As[0][0][0][0];
    gload_lds16(asrc + (size_t)tid * 8,        base + (size_t)tid * 16);
    gload_lds16(asrc + 2048 + (size_t)tid * 8, base + 4096 + (size_t)tid * 16);
    const float4* gp = (const float4*)gsrc;
    const float4* up = (const float4*)usrc;
    float4 tg0 = gp[0], tg1 = gp[1], tu0 = up[0], tu1 = up[1];
    *((u16x8*)&Gs[0][bq][brw][0]) = cvt8(tg0, tg1);
    *((u16x8*)&Us[0][bq][brw][0]) = cvt8(tu0, tu1);
    const float4* gp1 = (const float4*)(gsrc + 32);
    const float4* up1 = (const float4*)(usrc + 32);
    g0 = gp1[0]; g1 = gp1[1]; u0 = up1[0]; u1 = up1[1];
    WAIT_LGKM0(); SCHED_FENCE();
  }

  int cur = 0;
  const int NT = HID / 32;   // 32
  for (int t = 0; t < NT; ++t) {
    WAIT_VM4(); SCHED_FENCE();          // drains the (oldest) A-DMA pair; B loads stay in flight
    __builtin_amdgcn_s_barrier(); SCHED_FENCE();
    int nxt = cur ^ 1;
    int ka = (t + 1 < NT) ? (t + 1) * 32 : 0;   // wrapped dummy on last iter
    // issue next A DMA (linear, blocked xg)
    {
      char* base = (char*)&As[nxt][0][0][0];
      const unsigned short* ak = asrc + (size_t)ka * 128;
      gload_lds16(ak + (size_t)tid * 8,        base + (size_t)tid * 16);
      gload_lds16(ak + 2048 + (size_t)tid * 8, base + 4096 + (size_t)tid * 16);
    }
    SCHED_FENCE();
    // compute current tile (16 MFMA) -- free to interleave with cvt below
    {
      int kg = lane >> 4;
      int rl = lane & 15;
      bf16x8 af[4], gf[2], uf[2];
#pragma unroll
      for (int m = 0; m < 4; ++m)
        af[m] = *((const bf16x8*)&As[cur][kg][wm * 64 + m * 16 + rl][0]);
#pragma unroll
      for (int n = 0; n < 2; ++n) {
        int r = (wn * 32 + n * 16 + rl) ^ kg;
        gf[n] = *((const bf16x8*)&Gs[cur][kg][r][0]);
        uf[n] = *((const bf16x8*)&Us[cur][kg][r][0]);
      }
#pragma unroll
      for (int m = 0; m < 4; ++m)
#pragma unroll
        for (int n = 0; n < 2; ++n) {
          accg[m][n] = __builtin_amdgcn_mfma_f32_16x16x32_bf16(af[m], gf[n], accg[m][n], 0, 0, 0);
          accu[m][n] = __builtin_amdgcn_mfma_f32_16x16x32_bf16(af[m], uf[n], accu[m][n], 0, 0, 0);
        }
    }
    // stage B(t+1) regs -> LDS[nxt] (compiler inserts exact vmcnt for the reg deps)
    *((u16x8*)&Gs[nxt][bq][brw][0]) = cvt8(g0, g1);
    *((u16x8*)&Us[nxt][bq][brw][0]) = cvt8(u0, u1);
    SCHED_FENCE();                       // pin B(t+2) issue BELOW the cvt reads
    // issue B(t+2) register loads (covered until end of next iteration)
    {
      int kb = (t + 2 < NT) ? (t + 2) * 32 : 0;
      const float4* gp = (const float4*)(gsrc + kb);
      const float4* up = (const float4*)(usrc + kb);
      g0 = gp[0]; g1 = gp[1]; u0 = up[0]; u1 = up[1];
    }
    WAIT_LGKM0(); SCHED_FENCE();         // ds_writes visible before next barrier
    cur = nxt;
  }
  WAIT_VM0();                            // drain dummy prefetches

  int rl = lane & 15;
  int rq = lane >> 4;
  size_t hb_base = (size_t)((off + m0) >> 7) * (INTERN * 128);
#pragma unroll
  for (int m = 0; m < 4; ++m) {
#pragma unroll
    for (int n = 0; n < 2; ++n) {
      int col = n0 + wn * 32 + n * 16 + rl;
      size_t cbase = hb_base + (size_t)(col >> 3) * 1024 + (col & 7);
#pragma unroll
      for (int j = 0; j < 4; ++j) {
        int lr = wm * 64 + m * 16 + rq * 4 + j;
        if (m0 + lr < Ne) {
          float gv = accg[m][n][j];
          float uv = accu[m][n][j];
          float tt2 = gv + 0.044715f * gv * gv * gv;
          float a  = gv / (1.0f + __expf(-1.5957691216f * tt2));  // == gelu_pytorch_tanh
          hbuf[cbase + (size_t)lr * 8] = f32_to_bf16(a * uv);
        }
      }
    }
  }
}

// ---------------- GEMM2: y = h Wd^T (blocked-A, BK=64, late-B + vmcnt(4)) ----------------
__global__ __launch_bounds__(256, 2)
void gemm2_kernel(const unsigned short* __restrict__ hbuf,
                  const float* __restrict__ down,
                  const int* __restrict__ counts,
                  const int* __restrict__ offsets,
                  unsigned short* __restrict__ ybuf) {
  int e  = blockIdx.z;
  int Ne = counts[e];
  int m0 = blockIdx.y * 128;
  if (m0 >= Ne) return;
  int n0  = blockIdx.x * 64;
  int off = offsets[e];

  __shared__ __align__(16) unsigned short As[2][8][128][8];  // 32 KB
  __shared__ __align__(16) unsigned short Bs[2][8][64][8];   // 16 KB

  int tid  = threadIdx.x;
  int lane = tid & 63;
  int wave = tid >> 6;
  int wm = wave >> 1;
  int wn = wave & 1;

  const unsigned short* asrc = hbuf + (size_t)((off + m0) >> 7) * (INTERN * 128);

  int brow = tid >> 2;
  int bq   = tid & 3;
  int kgw0 = bq * 2, kgw1 = bq * 2 + 1;
  const float* bsrc = down + (size_t)e * HID * INTERN + (size_t)(n0 + brow) * INTERN + bq * 16;

  f32x4 acc[4][2];
#pragma unroll
  for (int m = 0; m < 4; ++m)
#pragma unroll
    for (int n = 0; n < 2; ++n) acc[m][n] = (f32x4){0.f, 0.f, 0.f, 0.f};

  float4 b0, b1, b2, b3;   // single in-flight B reg set

  // ---- prologue ----
  {
    char* base = (char*)&As[0][0][0][0];
#pragma unroll
    for (int o = 0; o < 4; ++o)
      gload_lds16(asrc + o * 2048 + (size_t)tid * 8, base + o * 4096 + (size_t)tid * 16);
    const float4* bp = (const float4*)bsrc;
    float4 t0 = bp[0], t1 = bp[1], t2 = bp[2], t3 = bp[3];
    *((u16x8*)&Bs[0][kgw0][brow ^ kgw0][0]) = cvt8(t0, t1);
    *((u16x8*)&Bs[0][kgw1][brow ^ kgw1][0]) = cvt8(t2, t3);
    const float4* bp1 = (const float4*)(bsrc + 64);
    b0 = bp1[0]; b1 = bp1[1]; b2 = bp1[2]; b3 = bp1[3];
    WAIT_LGKM0(); SCHED_FENCE();
  }

  int cur = 0;
  const int NT = INTERN / 64;   // 32
  for (int t = 0; t < NT; ++t) {
    WAIT_VM4(); SCHED_FENCE();          // drains the 4-oldest (A quad); B stays in flight
    __builtin_amdgcn_s_barrier(); SCHED_FENCE();
    int nxt = cur ^ 1;
    int ka = (t + 1 < NT) ? (t + 1) * 64 : 0;
    {
      char* base = (char*)&As[nxt][0][0][0];
      const unsigned short* ak = asrc + (size_t)ka * 128;
#pragma unroll
      for (int o = 0; o < 4; ++o)
        gload_lds16(ak + o * 2048 + (size_t)tid * 8, base + o * 4096 + (size_t)tid * 16);
    }
    SCHED_FENCE();
    // compute current tile
#pragma unroll
    for (int kk = 0; kk < 2; ++kk) {
      int kg = kk * 4 + (lane >> 4);
      int rl = lane & 15;
      bf16x8 af[4], bfv[2];
#pragma unroll
      for (int m = 0; m < 4; ++m)
        af[m] = *((const bf16x8*)&As[cur][kg][wm * 64 + m * 16 + rl][0]);
#pragma unroll
      for (int n = 0; n < 2; ++n)
        bfv[n] = *((const bf16x8*)&Bs[cur][kg][(wn * 32 + n * 16 + rl) ^ kg][0]);
#pragma unroll
      for (int m = 0; m < 4; ++m)
#pragma unroll
        for (int n = 0; n < 2; ++n)
          acc[m][n] = __builtin_amdgcn_mfma_f32_16x16x32_bf16(af[m], bfv[n], acc[m][n], 0, 0, 0);
    }
    // stage B(t+1) -> LDS[nxt]
    *((u16x8*)&Bs[nxt][kgw0][brow ^ kgw0][0]) = cvt8(b0, b1);
    *((u16x8*)&Bs[nxt][kgw1][brow ^ kgw1][0]) = cvt8(b2, b3);
    SCHED_FENCE();
    // issue B(t+2)
    {
      int kb = (t + 2 < NT) ? (t + 2) * 64 : 0;
      const float4* bp = (const float4*)(bsrc + kb);
      b0 = bp[0]; b1 = bp[1]; b2 = bp[2]; b3 = bp[3];
    }
    WAIT_LGKM0(); SCHED_FENCE();
    cur = nxt;
  }
  WAIT_VM0();

  int rl = lane & 15;
  int rq = lane >> 4;
#pragma unroll
  for (int m = 0; m < 4; ++m) {
#pragma unroll
    for (int n = 0; n < 2; ++n) {
      int col = n0 + wn * 32 + n * 16 + rl;
#pragma unroll
      for (int j = 0; j < 4; ++j) {
        int lr = wm * 64 + m * 16 + rq * 4 + j;
        if (m0 + lr < Ne)
          ybuf[(size_t)(off + m0 + lr) * HID + col] = f32_to_bf16(acc[m][n][j]);
      }
    }
  }
}

// ---------------- final combine ----------------
__global__ void combine_kernel(const int* __restrict__ pos_map,
                               const float* __restrict__ wgt_map,
                               const unsigned short* __restrict__ ybuf,
                               float* __restrict__ out) {
  int i  = blockIdx.x * 256 + threadIdx.x;
  int t  = i >> 7;
  int c8 = i & 127;
  int p0 = pos_map[2 * t];
  int p1 = pos_map[2 * t + 1];
  float w0 = wgt_map[2 * t];
  float w1 = wgt_map[2 * t + 1];
  float acc[8];
#pragma unroll
  for (int j = 0; j < 8; ++j) acc[j] = 0.f;
  if (p0 >= 0) {
    u16x8 v = *((const u16x8*)(ybuf + (size_t)p0 * HID + c8 * 8));
#pragma unroll
    for (int j = 0; j < 8; ++j) acc[j] += w0 * bf16_to_f32(v[j]);
  }
  if (p1 >= 0) {
    u16x8 v = *((const u16x8*)(ybuf + (size_t)p1 * HID + c8 * 8));
#pragma unroll
    for (int j = 0; j < 8; ++j) acc[j] += w1 * bf16_to_f32(v[j]);
  }
  float4 o0 = make_float4(acc[0], acc[1], acc[2], acc[3]);
  float4 o1 = make_float4(acc[4], acc[5], acc[6], acc[7]);
  float4* dst = (float4*)(out + (size_t)t * HID + c8 * 8);
  dst[0] = o0;
  dst[1] = o1;
}

// ---------------- launch ----------------
extern "C" void kernel_launch(void* const* d_in, const int* in_sizes, int n_in,
                              void* d_out, int out_size, void* d_ws, size_t ws_size,
                              hipStream_t stream) {
  (void)in_sizes; (void)n_in; (void)out_size;
  const float* hidden = (const float*)d_in[0];
  const int*   tki    = (const int*)d_in[1];
  const float* tkw    = (const float*)d_in[2];
  const float* gup    = (const float*)d_in[3];
  const float* down   = (const float*)d_in[4];
  float* out = (float*)d_out;
  char*  ws  = (char*)d_ws;

  int*   counts   = (int*)  (ws + 0);
  int*   offsets  = (int*)  (ws + 64);
  int*   tok_list = (int*)  (ws + 256);
  int*   pos_map  = (int*)  (ws + 65792);
  float* wgt_map  = (float*)(ws + 82176);
  float* w_list   = (float*)(ws + 98560);
  unsigned short* hbuf = (unsigned short*)(ws + 4358400);   // MAXPOS*2048 bf16 (blocked)
  unsigned short* ybuf = (unsigned short*)(ws + 25854208);  // MAXPOS*1024 bf16
  unsigned short* xg   = ybuf;  // alias: xg fully consumed by gemm1 before gemm2 writes ybuf

  if (ws_size < 36602112ull) return;

  hipLaunchKernelGGL(route_kernel, dim3(1), dim3(256), 0, stream,
                     tki, tkw, counts, offsets, tok_list, w_list, pos_map, wgt_map);
  hipLaunchKernelGGL(gather_cvt_x_kernel, dim3(MAXPOS / 2), dim3(256), 0, stream,
                     hidden, counts, offsets, tok_list, xg);
  hipLaunchKernelGGL(gemm1_kernel, dim3(INTERN / 64, T_TOK / 128, NEXP), dim3(256), 0, stream,
                     xg, gup, counts, offsets, hbuf);
  hipLaunchKernelGGL(gemm2_kernel, dim3(HID / 64, T_TOK / 128, NEXP), dim3(256), 0, stream,
                     hbuf, down, counts, offsets, ybuf);
  hipLaunchKernelGGL(combine_kernel, dim3(T_TOK * HID / 8 / 256), dim3(256), 0, stream,
                     pos_map, wgt_map, ybuf, out);
}